// Round 3
// baseline (248.108 us; speedup 1.0000x reference)
//
#include <hip/hip_runtime.h>
#include <math.h>

#define BQ   4
#define QN   256
#define KN   1024
#define DIN  256     // Q_SIZE == K_SIZE == V_SIZE
#define HD   128     // H

// ---------------------------------------------------------------------------
// Kernel 1: projections.  16 rows/block, 256 threads.
//   blocks [0, 64)   : queries x W_q -> qp   [B*QN][HD]   (row-major)
//   blocks [64, 320) : keys    x W_k -> kpT  [B][HD][KN]  (TRANSPOSED)
// W i-tiles staged in LDS (stride 36 floats: 16B-aligned rows, conflict-free);
// x rows read via wave-uniform scalar loads.
// ---------------------------------------------------------------------------
__global__ __launch_bounds__(256, 2) void proj_kernel(const float* __restrict__ queries,
                                                      const float* __restrict__ keys,
                                                      const float* __restrict__ W_q,
                                                      const float* __restrict__ W_k,
                                                      float* __restrict__ qp,
                                                      float* __restrict__ kpT) {
    __shared__ float Wt[HD][36];          // i-tile of 32, padded to 36

    const int t = threadIdx.x;
    const int blk = blockIdx.x;
    const bool is_q = blk < (BQ * QN) / 16;
    const float* x = is_q ? queries : keys;
    const float* W = is_q ? W_q : W_k;
    const int row0 = (is_q ? blk : blk - (BQ * QN) / 16) * 16;

    const int h = t & 127;
    const int g = __builtin_amdgcn_readfirstlane(t >> 7);  // wave-uniform row half

    float acc[8] = {0.f, 0.f, 0.f, 0.f, 0.f, 0.f, 0.f, 0.f};

    for (int tile = 0; tile < 8; tile++) {
        const int i0 = tile * 32;
        __syncthreads();
        // stage W[:, i0:i0+32] -> Wt (coalesced global, uniform-spread LDS writes)
#pragma unroll
        for (int u = 0; u < 4; u++) {
            const int hs = (t >> 3) + 32 * u;
            const int is = (4 * t) & 31;
            float4 wv = *(const float4*)(W + (size_t)hs * DIN + i0 + is);
            *(float4*)&Wt[hs][is] = wv;
        }
        __syncthreads();
#pragma unroll 4
        for (int ii = 0; ii < 32; ii += 4) {
            float4 wv = *(const float4*)&Wt[h][ii];
#pragma unroll
            for (int j = 0; j < 8; j++) {
                const float* xr = x + (size_t)(row0 + g * 8 + j) * DIN + i0 + ii;  // uniform -> s_load
                float4 xv = *(const float4*)xr;
                acc[j] = __builtin_fmaf(wv.x, xv.x,
                         __builtin_fmaf(wv.y, xv.y,
                         __builtin_fmaf(wv.z, xv.z,
                         __builtin_fmaf(wv.w, xv.w, acc[j]))));
            }
        }
    }

    if (is_q) {
        float* dst = qp + (size_t)(row0 + g * 8) * HD + h;
#pragma unroll
        for (int j = 0; j < 8; j++) dst[(size_t)j * HD] = acc[j];
    } else {
        const int b = row0 >> 10, kk = row0 & (KN - 1);
        float* dst = kpT + ((size_t)b * HD + h) * KN + kk + g * 8;
#pragma unroll
        for (int j = 0; j < 8; j++) dst[j] = acc[j];     // scattered, tiny total (2 MB)
    }
}

// ---------------------------------------------------------------------------
// Kernel 2: scores + masked softmax -> normalized attention weights (4 MB ws).
// Grid = B * QN/2 = 512 blocks (batch-minor), 256 threads.
// Thread owns k = t + 256j (j=0..3, stride ownership: every wave load-balanced).
// score(k,q) = Sw - 2*sum_h w[h]*rcp(exp2(C2*(qp+kp)) + 1);  Sw constant ->
// dropped (softmax shift-invariant).  kpT reads coalesced (lanes = consecutive k).
// Writes weight 0 for k >= valid so the AV kernel needs no masking.
// ---------------------------------------------------------------------------
__global__ __launch_bounds__(256, 2) void score_kernel(const float* __restrict__ qp,
                                                       const float* __restrict__ kpT,
                                                       const int* __restrict__ valid_lens,
                                                       const float* __restrict__ w_v,
                                                       float* __restrict__ attn) {
    __shared__ float4 s_pack[HD];   // (w, C2*qp0, C2*qp1, -)
    __shared__ float s_red[8];      // per-wave max, [wave*2 + q]
    __shared__ float s_sum[8];
    __shared__ float s_fin[4];      // m0, m1, inv0, inv1

    const int blk = blockIdx.x;
    const int b = blk & 3;
    const int q0 = (blk >> 2) * 2;
    const int t = threadIdx.x;
    const float C2 = 2.8853900817779268f;        // 2*log2(e)

    if (t < HD) {
        float w  = w_v[t];
        float p0 = qp[(size_t)(b * QN + q0) * HD + t];
        float p1 = qp[(size_t)(b * QN + q0 + 1) * HD + t];
        s_pack[t] = make_float4(w, C2 * p0, C2 * p1, 0.f);
    }
    const int valid = valid_lens[b];
    __syncthreads();

    const float* kb = kpT + (size_t)b * HD * KN + t;
    float a0[4] = {0.f, 0.f, 0.f, 0.f};
    float a1[4] = {0.f, 0.f, 0.f, 0.f};

    for (int h = 0; h < HD; h++) {
        float4 p = s_pack[h];
        const float* kr = kb + (size_t)h * KN;
#pragma unroll
        for (int j = 0; j < 4; j++) {
            if (t + 256 * j < valid) {
                float kv = kr[256 * j];
                float g0 = __builtin_amdgcn_exp2f(__builtin_fmaf(C2, kv, p.y));
                a0[j] += p.x * __builtin_amdgcn_rcpf(g0 + 1.0f);
                float g1 = __builtin_amdgcn_exp2f(__builtin_fmaf(C2, kv, p.z));
                a1[j] += p.x * __builtin_amdgcn_rcpf(g1 + 1.0f);
            }
        }
    }

    // scores in exp2 domain: S = -2*log2e*a
    const float NL2E = -2.8853900817779268f;     // -2*log2(e)
    float S0[4], S1[4];
    float m0 = -INFINITY, m1 = -INFINITY;
#pragma unroll
    for (int j = 0; j < 4; j++) {
        S0[j] = NL2E * a0[j];
        S1[j] = NL2E * a1[j];
        if (t + 256 * j < valid) {
            m0 = fmaxf(m0, S0[j]);
            m1 = fmaxf(m1, S1[j]);
        }
    }
#pragma unroll
    for (int off = 32; off > 0; off >>= 1) {
        m0 = fmaxf(m0, __shfl_xor(m0, off, 64));
        m1 = fmaxf(m1, __shfl_xor(m1, off, 64));
    }
    const int wv = t >> 6;
    if ((t & 63) == 0) { s_red[wv * 2] = m0; s_red[wv * 2 + 1] = m1; }
    __syncthreads();
    if (t == 0) {
        s_fin[0] = fmaxf(fmaxf(s_red[0], s_red[2]), fmaxf(s_red[4], s_red[6]));
        s_fin[1] = fmaxf(fmaxf(s_red[1], s_red[3]), fmaxf(s_red[5], s_red[7]));
    }
    __syncthreads();
    m0 = s_fin[0]; m1 = s_fin[1];

    float e0[4], e1[4], sum0 = 0.f, sum1 = 0.f;
#pragma unroll
    for (int j = 0; j < 4; j++) {
        const bool act = (t + 256 * j) < valid;
        e0[j] = act ? __builtin_amdgcn_exp2f(S0[j] - m0) : 0.f;
        e1[j] = act ? __builtin_amdgcn_exp2f(S1[j] - m1) : 0.f;
        sum0 += e0[j];
        sum1 += e1[j];
    }
#pragma unroll
    for (int off = 32; off > 0; off >>= 1) {
        sum0 += __shfl_xor(sum0, off, 64);
        sum1 += __shfl_xor(sum1, off, 64);
    }
    if ((t & 63) == 0) { s_sum[wv * 2] = sum0; s_sum[wv * 2 + 1] = sum1; }
    __syncthreads();
    if (t == 0) {
        s_fin[2] = 1.0f / (s_sum[0] + s_sum[2] + s_sum[4] + s_sum[6]);
        s_fin[3] = 1.0f / (s_sum[1] + s_sum[3] + s_sum[5] + s_sum[7]);
    }
    __syncthreads();
    const float inv0 = s_fin[2], inv1 = s_fin[3];

    float* arow0 = attn + (size_t)(b * QN + q0) * KN + t;
    float* arow1 = arow0 + KN;
#pragma unroll
    for (int j = 0; j < 4; j++) {
        arow0[256 * j] = e0[j] * inv0;
        arow1[256 * j] = e1[j] * inv1;
    }
}

// ---------------------------------------------------------------------------
// Kernel 3: out[b,q,v] = sum_k attn[b,q,k] * values[b,k,v].
// Grid = B x 16 q-tiles x 4 v-quarters = 256 blocks, 256 threads.
// Block tile: 16 q x 64 v; thread owns (q = t>>4, 4 v).  attn tile staged in
// LDS (stride 68: aligned, uniform banks); values float4 coalesced; k >= valid
// has attn == 0 so only tile-level early exit is needed.
// ---------------------------------------------------------------------------
__global__ __launch_bounds__(256, 2) void av_kernel(const float* __restrict__ attn,
                                                    const float* __restrict__ values,
                                                    const int* __restrict__ valid_lens,
                                                    float* __restrict__ out) {
    __shared__ float s_a[16][68];

    const int blk = blockIdx.x;
    const int b = blk & 3;
    const int qt = (blk >> 2) & 15;
    const int vb = blk >> 6;
    const int t = threadIdx.x;
    const int q = t >> 4;
    const int q0 = qt * 16;
    const int voff = vb * 64 + (t & 15) * 4;
    const int valid = valid_lens[b];

    const float* arow = attn + (size_t)(b * QN + q0 + q) * KN + (t & 15) * 4;
    const float* vp = values + (size_t)b * KN * DIN + voff;

    float4 acc = {0.f, 0.f, 0.f, 0.f};
    for (int kt = 0; kt < valid; kt += 64) {
        __syncthreads();
        *(float4*)&s_a[q][(t & 15) * 4] = *(const float4*)(arow + kt);
        __syncthreads();
#pragma unroll 4
        for (int kk = 0; kk < 64; kk += 4) {
            float4 aw = *(const float4*)&s_a[q][kk];
            float4 v0 = *(const float4*)(vp + (size_t)(kt + kk) * DIN);
            float4 v1 = *(const float4*)(vp + (size_t)(kt + kk + 1) * DIN);
            float4 v2 = *(const float4*)(vp + (size_t)(kt + kk + 2) * DIN);
            float4 v3 = *(const float4*)(vp + (size_t)(kt + kk + 3) * DIN);
            acc.x += aw.x * v0.x + aw.y * v1.x + aw.z * v2.x + aw.w * v3.x;
            acc.y += aw.x * v0.y + aw.y * v1.y + aw.z * v2.y + aw.w * v3.y;
            acc.z += aw.x * v0.z + aw.y * v1.z + aw.z * v2.z + aw.w * v3.z;
            acc.w += aw.x * v0.w + aw.y * v1.w + aw.z * v2.w + aw.w * v3.w;
        }
    }
    *(float4*)(out + (size_t)(b * QN + q0 + q) * DIN + voff) = acc;
}

extern "C" void kernel_launch(void* const* d_in, const int* in_sizes, int n_in,
                              void* d_out, int out_size, void* d_ws, size_t ws_size,
                              hipStream_t stream) {
    const float* queries    = (const float*)d_in[0];
    const float* keys       = (const float*)d_in[1];
    const float* values     = (const float*)d_in[2];
    const int*   valid_lens = (const int*)d_in[3];
    const float* W_q        = (const float*)d_in[4];
    const float* W_k        = (const float*)d_in[5];
    const float* w_v        = (const float*)d_in[6];
    float* out = (float*)d_out;

    float* qp   = (float*)d_ws;                    // [B*QN][HD]    512 KB
    float* kpT  = qp + (size_t)BQ * QN * HD;       // [B][HD][KN]     2 MB
    float* attn = kpT + (size_t)BQ * HD * KN;      // [B*QN][KN]      4 MB

    proj_kernel<<<(BQ * QN + BQ * KN) / 16, 256, 0, stream>>>(queries, keys, W_q, W_k, qp, kpT);
    score_kernel<<<BQ * QN / 2, 256, 0, stream>>>(qp, kpT, valid_lens, w_v, attn);
    av_kernel<<<BQ * (QN / 16) * 4, 256, 0, stream>>>(attn, values, valid_lens, out);
}

// Round 4
// 150.768 us; speedup vs baseline: 1.6456x; 1.6456x over previous
//
#include <hip/hip_runtime.h>
#include <math.h>

#define BQ   4
#define QN   256
#define KN   1024
#define DIN  256     // Q_SIZE == K_SIZE == V_SIZE
#define HD   128     // H

// ---------------------------------------------------------------------------
// Kernel 1: projections as a tiled GEMM.  [5120 x 256] x [256 x 128].
// Rows 0..1023  = queries -> qp  [B*QN][HD]  (row-major)
// Rows 1024..   = keys    -> kpT [B][HD][KN] (transposed for score kernel)
// Block = 32 rows x 128 h, 256 threads, thread = 4 rows x 4 h (16 acc).
// K staged in LDS slices of 32, both operands transposed to [k][*]:
//   xT stride 36, WT stride 136 (16B-aligned, conflict-free b128 reads).
// ---------------------------------------------------------------------------
__global__ __launch_bounds__(256, 2) void proj_kernel(const float* __restrict__ queries,
                                                      const float* __restrict__ keys,
                                                      const float* __restrict__ W_q,
                                                      const float* __restrict__ W_k,
                                                      float* __restrict__ qp,
                                                      float* __restrict__ kpT) {
    __shared__ float xT[32][36];    // [k][row]
    __shared__ float WT[32][136];   // [k][h]

    const int t = threadIdx.x;
    const int row0 = blockIdx.x * 32;
    const bool is_q = row0 < BQ * QN;
    const float* x = is_q ? queries : keys;
    const float* W = is_q ? W_q : W_k;
    const int xr0 = is_q ? row0 : row0 - BQ * QN;

    const int h0 = (t & 31) * 4;        // 4 h columns
    const int r0 = (t >> 5) * 4;        // 4 rows

    float acc[4][4];
#pragma unroll
    for (int r = 0; r < 4; r++)
#pragma unroll
        for (int c = 0; c < 4; c++) acc[r][c] = 0.f;

    for (int ks = 0; ks < DIN; ks += 32) {
        __syncthreads();
        {   // stage x[32 rows][32 k] -> xT[k][row]
            const int r = t >> 3, k4 = (t & 7) * 4;
            float4 xv = *(const float4*)(x + (size_t)(xr0 + r) * DIN + ks + k4);
            xT[k4 + 0][r] = xv.x; xT[k4 + 1][r] = xv.y;
            xT[k4 + 2][r] = xv.z; xT[k4 + 3][r] = xv.w;
        }
#pragma unroll
        for (int u = 0; u < 4; u++) {   // stage W[128 h][32 k] -> WT[k][h]
            const int h = (t >> 3) + 32 * u, k4 = (t & 7) * 4;
            float4 wv = *(const float4*)(W + (size_t)h * DIN + ks + k4);
            WT[k4 + 0][h] = wv.x; WT[k4 + 1][h] = wv.y;
            WT[k4 + 2][h] = wv.z; WT[k4 + 3][h] = wv.w;
        }
        __syncthreads();
#pragma unroll
        for (int kk = 0; kk < 32; kk++) {
            float4 xv = *(const float4*)&xT[kk][r0];
            float4 wv = *(const float4*)&WT[kk][h0];
            const float xr[4] = {xv.x, xv.y, xv.z, xv.w};
            const float wc[4] = {wv.x, wv.y, wv.z, wv.w};
#pragma unroll
            for (int r = 0; r < 4; r++)
#pragma unroll
                for (int c = 0; c < 4; c++)
                    acc[r][c] = __builtin_fmaf(xr[r], wc[c], acc[r][c]);
        }
    }

    if (is_q) {
#pragma unroll
        for (int r = 0; r < 4; r++)
            *(float4*)(qp + (size_t)(row0 + r0 + r) * HD + h0) =
                make_float4(acc[r][0], acc[r][1], acc[r][2], acc[r][3]);
    } else {
        const int krow = row0 - BQ * QN;
        const int b = krow >> 10, k0 = (krow & (KN - 1)) + r0;
#pragma unroll
        for (int c = 0; c < 4; c++)
            *(float4*)(kpT + ((size_t)(b * HD + h0 + c)) * KN + k0) =
                make_float4(acc[0][c], acc[1][c], acc[2][c], acc[3][c]);
    }
}

// ---------------------------------------------------------------------------
// Kernel 2: scores -> unnormalized softmax numerators e + partial row sums.
// Grid = B x 32 q-tiles(8) x 4 k-chunks(256) = 512 blocks, 256 threads.
// Thread owns one k, 8 q accumulators: each kv load feeds 40 VALU ops.
// score = -2*log2e * sum_h w[h]*rcp(exp2(2*log2e*(qp+kp)) + 1)   (+const dropped;
// softmax shift-invariant).  No max-subtraction: |score| <= sum|w| ~ 9, safe.
// e = 0 for k >= valid.  Partial sums -> ws (deterministic, no atomics).
// ---------------------------------------------------------------------------
__global__ __launch_bounds__(256, 2) void score_kernel(const float* __restrict__ qp,
                                                       const float* __restrict__ kpT,
                                                       const int* __restrict__ valid_lens,
                                                       const float* __restrict__ w_v,
                                                       float* __restrict__ attn,
                                                       float* __restrict__ partial) {
    __shared__ float s_w[HD];
    __shared__ float s_pq[HD][8];   // C2 * qp[h][q]
    __shared__ float s_red[4][8];

    const int blk = blockIdx.x;
    const int b = blk & 3;
    const int q0 = ((blk >> 2) & 31) * 8;
    const int c = blk >> 7;
    const int t = threadIdx.x;
    const int k = c * 256 + t;
    const float C2 = 2.8853900817779268f;     // 2*log2(e)
    const float NL2E = -2.8853900817779268f;

    const int valid = valid_lens[b];
    float* pp = partial + (size_t)(b * QN + q0) * 4;

    if (c * 256 >= valid) {                   // whole chunk masked: attn never read here
        if (t < 8) pp[t * 4 + c] = 0.f;
        return;
    }

    if (t < HD) s_w[t] = w_v[t];
    {
        const int h = t & 127;
#pragma unroll
        for (int j = 0; j < 4; j++) {
            const int q = (t >> 7) * 4 + j;
            s_pq[h][q] = C2 * qp[(size_t)(b * QN + q0 + q) * HD + h];
        }
    }
    __syncthreads();

    const float* kcol = kpT + (size_t)(b * HD) * KN + k;
    float acc[8] = {0.f, 0.f, 0.f, 0.f, 0.f, 0.f, 0.f, 0.f};

#pragma unroll 4
    for (int h = 0; h < HD; h++) {
        const float kv2 = C2 * kcol[(size_t)h * KN];
        const float w = s_w[h];
        float4 p0 = *(const float4*)&s_pq[h][0];
        float4 p1 = *(const float4*)&s_pq[h][4];
        acc[0] += w * __builtin_amdgcn_rcpf(__builtin_amdgcn_exp2f(kv2 + p0.x) + 1.0f);
        acc[1] += w * __builtin_amdgcn_rcpf(__builtin_amdgcn_exp2f(kv2 + p0.y) + 1.0f);
        acc[2] += w * __builtin_amdgcn_rcpf(__builtin_amdgcn_exp2f(kv2 + p0.z) + 1.0f);
        acc[3] += w * __builtin_amdgcn_rcpf(__builtin_amdgcn_exp2f(kv2 + p0.w) + 1.0f);
        acc[4] += w * __builtin_amdgcn_rcpf(__builtin_amdgcn_exp2f(kv2 + p1.x) + 1.0f);
        acc[5] += w * __builtin_amdgcn_rcpf(__builtin_amdgcn_exp2f(kv2 + p1.y) + 1.0f);
        acc[6] += w * __builtin_amdgcn_rcpf(__builtin_amdgcn_exp2f(kv2 + p1.z) + 1.0f);
        acc[7] += w * __builtin_amdgcn_rcpf(__builtin_amdgcn_exp2f(kv2 + p1.w) + 1.0f);
    }

    const bool act = k < valid;
    const int wv = t >> 6;
    float* arow = attn + (size_t)(b * QN + q0) * KN + k;
#pragma unroll
    for (int q = 0; q < 8; q++) {
        float e = act ? __builtin_amdgcn_exp2f(NL2E * acc[q]) : 0.f;
        arow[(size_t)q * KN] = e;
        // block-wide sum of e over the 256 k of this chunk
#pragma unroll
        for (int off = 32; off > 0; off >>= 1) e += __shfl_xor(e, off, 64);
        if ((t & 63) == 0) s_red[wv][q] = e;
    }
    __syncthreads();
    if (t < 8)
        pp[t * 4 + c] = s_red[0][t] + s_red[1][t] + s_red[2][t] + s_red[3][t];
}

// ---------------------------------------------------------------------------
// Kernel 3: out[b,q,v] = (1/rowsum) * sum_k e[b,q,k] * values[b,k,v].
// Grid = B x 16 q-tiles x 4 v-quarters = 256 blocks, 256 threads.
// Thread = (q = t>>4, 4 v).  e tile staged in LDS (stride 68); rowsum from
// the 4 chunk partials (normalization fused here).
// ---------------------------------------------------------------------------
__global__ __launch_bounds__(256, 2) void av_kernel(const float* __restrict__ attn,
                                                    const float* __restrict__ partial,
                                                    const float* __restrict__ values,
                                                    const int* __restrict__ valid_lens,
                                                    float* __restrict__ out) {
    __shared__ float s_a[16][68];

    const int blk = blockIdx.x;
    const int b = blk & 3;
    const int qt = (blk >> 2) & 15;
    const int vb = blk >> 6;
    const int t = threadIdx.x;
    const int q = t >> 4;
    const int q0 = qt * 16;
    const int voff = vb * 64 + (t & 15) * 4;
    const int valid = valid_lens[b];

    float4 ps = *(const float4*)(partial + (size_t)(b * QN + q0 + q) * 4);
    const float inv = 1.0f / (ps.x + ps.y + ps.z + ps.w);

    const float* arow = attn + (size_t)(b * QN + q0 + q) * KN + (t & 15) * 4;
    const float* vp = values + (size_t)b * KN * DIN + voff;

    float4 acc = {0.f, 0.f, 0.f, 0.f};
    for (int kt = 0; kt < valid; kt += 64) {
        __syncthreads();
        *(float4*)&s_a[q][(t & 15) * 4] = *(const float4*)(arow + kt);
        __syncthreads();
#pragma unroll 4
        for (int kk = 0; kk < 64; kk += 4) {
            float4 aw = *(const float4*)&s_a[q][kk];
            float4 v0 = *(const float4*)(vp + (size_t)(kt + kk) * DIN);
            float4 v1 = *(const float4*)(vp + (size_t)(kt + kk + 1) * DIN);
            float4 v2 = *(const float4*)(vp + (size_t)(kt + kk + 2) * DIN);
            float4 v3 = *(const float4*)(vp + (size_t)(kt + kk + 3) * DIN);
            acc.x += aw.x * v0.x + aw.y * v1.x + aw.z * v2.x + aw.w * v3.x;
            acc.y += aw.x * v0.y + aw.y * v1.y + aw.z * v2.y + aw.w * v3.y;
            acc.z += aw.x * v0.z + aw.y * v1.z + aw.z * v2.z + aw.w * v3.z;
            acc.w += aw.x * v0.w + aw.y * v1.w + aw.z * v2.w + aw.w * v3.w;
        }
    }
    acc.x *= inv; acc.y *= inv; acc.z *= inv; acc.w *= inv;
    *(float4*)(out + (size_t)(b * QN + q0 + q) * DIN + voff) = acc;
}

extern "C" void kernel_launch(void* const* d_in, const int* in_sizes, int n_in,
                              void* d_out, int out_size, void* d_ws, size_t ws_size,
                              hipStream_t stream) {
    const float* queries    = (const float*)d_in[0];
    const float* keys       = (const float*)d_in[1];
    const float* values     = (const float*)d_in[2];
    const int*   valid_lens = (const int*)d_in[3];
    const float* W_q        = (const float*)d_in[4];
    const float* W_k        = (const float*)d_in[5];
    const float* w_v        = (const float*)d_in[6];
    float* out = (float*)d_out;

    float* qp      = (float*)d_ws;                    // [B*QN][HD]    512 KB
    float* kpT     = qp + (size_t)BQ * QN * HD;       // [B][HD][KN]     2 MB
    float* attn    = kpT + (size_t)BQ * HD * KN;      // [B*QN][KN]      4 MB
    float* partial = attn + (size_t)BQ * QN * KN;     // [B*QN][4]      16 KB

    proj_kernel<<<(BQ * QN + BQ * KN) / 32, 256, 0, stream>>>(queries, keys, W_q, W_k, qp, kpT);
    score_kernel<<<BQ * (QN / 8) * 4, 256, 0, stream>>>(qp, kpT, valid_lens, w_v, attn, partial);
    av_kernel<<<BQ * (QN / 16) * 4, 256, 0, stream>>>(attn, partial, values, valid_lens, out);
}

// Round 5
// 127.914 us; speedup vs baseline: 1.9396x; 1.1787x over previous
//
#include <hip/hip_runtime.h>
#include <math.h>

#define BQ   4
#define QN   256
#define KN   1024
#define DIN  256     // Q_SIZE == K_SIZE == V_SIZE
#define HD   128     // H

// C2 = 2*log2(e): exp2(C2*x) = e^{2x}
#define C2F   2.8853900817779268f
#define NL2E  (-2.8853900817779268f)

// ---------------------------------------------------------------------------
// Kernel 1: projections as tiled GEMM, output in EXP2 DOMAIN:
//   Eq[b*QN+q][h] = exp2(C2*qp),  EkT[b][h][k] = exp2(C2*kp)  (transposed)
// Block = 32 rows x 128 h, 256 threads, thread = 4x4 = 16 acc.
// ---------------------------------------------------------------------------
__global__ __launch_bounds__(256, 2) void proj_kernel(const float* __restrict__ queries,
                                                      const float* __restrict__ keys,
                                                      const float* __restrict__ W_q,
                                                      const float* __restrict__ W_k,
                                                      float* __restrict__ Eq,
                                                      float* __restrict__ EkT) {
    __shared__ float xT[32][36];    // [k][row]
    __shared__ float WT[32][136];   // [k][h]

    const int t = threadIdx.x;
    const int row0 = blockIdx.x * 32;
    const bool is_q = row0 < BQ * QN;
    const float* x = is_q ? queries : keys;
    const float* W = is_q ? W_q : W_k;
    const int xr0 = is_q ? row0 : row0 - BQ * QN;

    const int h0 = (t & 31) * 4;
    const int r0 = (t >> 5) * 4;

    float acc[4][4];
#pragma unroll
    for (int r = 0; r < 4; r++)
#pragma unroll
        for (int c = 0; c < 4; c++) acc[r][c] = 0.f;

    for (int ks = 0; ks < DIN; ks += 32) {
        __syncthreads();
        {   // x[32 rows][32 k] -> xT[k][row]
            const int r = t >> 3, k4 = (t & 7) * 4;
            float4 xv = *(const float4*)(x + (size_t)(xr0 + r) * DIN + ks + k4);
            xT[k4 + 0][r] = xv.x; xT[k4 + 1][r] = xv.y;
            xT[k4 + 2][r] = xv.z; xT[k4 + 3][r] = xv.w;
        }
#pragma unroll
        for (int u = 0; u < 4; u++) {   // W[128 h][32 k] -> WT[k][h]
            const int h = (t >> 3) + 32 * u, k4 = (t & 7) * 4;
            float4 wv = *(const float4*)(W + (size_t)h * DIN + ks + k4);
            WT[k4 + 0][h] = wv.x; WT[k4 + 1][h] = wv.y;
            WT[k4 + 2][h] = wv.z; WT[k4 + 3][h] = wv.w;
        }
        __syncthreads();
#pragma unroll
        for (int kk = 0; kk < 32; kk++) {
            float4 xv = *(const float4*)&xT[kk][r0];
            float4 wv = *(const float4*)&WT[kk][h0];
            const float xr[4] = {xv.x, xv.y, xv.z, xv.w};
            const float wc[4] = {wv.x, wv.y, wv.z, wv.w};
#pragma unroll
            for (int r = 0; r < 4; r++)
#pragma unroll
                for (int c = 0; c < 4; c++)
                    acc[r][c] = __builtin_fmaf(xr[r], wc[c], acc[r][c]);
        }
    }

    if (is_q) {
#pragma unroll
        for (int r = 0; r < 4; r++) {
            float4 o;
            o.x = __builtin_amdgcn_exp2f(C2F * acc[r][0]);
            o.y = __builtin_amdgcn_exp2f(C2F * acc[r][1]);
            o.z = __builtin_amdgcn_exp2f(C2F * acc[r][2]);
            o.w = __builtin_amdgcn_exp2f(C2F * acc[r][3]);
            *(float4*)(Eq + (size_t)(row0 + r0 + r) * HD + h0) = o;
        }
    } else {
        const int krow = row0 - BQ * QN;
        const int b = krow >> 10, k0 = (krow & (KN - 1)) + r0;
#pragma unroll
        for (int c = 0; c < 4; c++) {
            float4 o;
            o.x = __builtin_amdgcn_exp2f(C2F * acc[0][c]);
            o.y = __builtin_amdgcn_exp2f(C2F * acc[1][c]);
            o.z = __builtin_amdgcn_exp2f(C2F * acc[2][c]);
            o.w = __builtin_amdgcn_exp2f(C2F * acc[3][c]);
            *(float4*)(EkT + ((size_t)(b * HD + h0 + c)) * KN + k0) = o;
        }
    }
}

// ---------------------------------------------------------------------------
// Kernel 2: scores -> unnormalized e + per-chunk row sums.
// Grid = 4b x 32 q-tiles(8) x 8 k-chunks(128) = 1024 blocks, 256 threads.
// Thread = (k-lane kl = t&127, h-half hh = t>>7).  Inner op per (q,k,h):
//   acc += w * rcp(fma(Ek, Eq, 1))   -- ONE transcendental.
// h-halves reduced through LDS; e = 0 for k >= valid; partial sums -> ws.
// ---------------------------------------------------------------------------
__global__ __launch_bounds__(256, 4) void score_kernel(const float* __restrict__ Eq,
                                                       const float* __restrict__ EkT,
                                                       const int* __restrict__ valid_lens,
                                                       const float* __restrict__ w_v,
                                                       float* __restrict__ attn,
                                                       float* __restrict__ partial) {
    __shared__ float s_w[HD];
    __shared__ float s_pq[HD][8];
    __shared__ float s_part[2][8][128];
    __shared__ float s_red[4][4];

    const int blk = blockIdx.x;
    const int b = blk & 3;
    const int q0 = ((blk >> 2) & 31) * 8;
    const int c = blk >> 7;            // 0..7
    const int t = threadIdx.x;
    const int valid = valid_lens[b];
    float* pp = partial + (size_t)(b * QN + q0) * 8;

    if (c * 128 >= valid) {            // fully masked chunk: attn never read here
        if (t < 8) pp[t * 8 + c] = 0.f;
        return;
    }

    const int kl = t & 127;
    const int hh = t >> 7;
    const int k = c * 128 + kl;

    if (t < HD) s_w[t] = w_v[t];
    {
        const int h = t & 127;
#pragma unroll
        for (int j = 0; j < 4; j++) {
            const int q = (t >> 7) * 4 + j;
            s_pq[h][q] = Eq[(size_t)(b * QN + q0 + q) * HD + h];
        }
    }
    __syncthreads();

    const float* kcol = EkT + (size_t)(b * HD + hh * 64) * KN + k;
    float acc[8] = {0.f, 0.f, 0.f, 0.f, 0.f, 0.f, 0.f, 0.f};

#pragma unroll 4
    for (int i = 0; i < 64; i++) {
        const float ek = kcol[(size_t)i * KN];
        const int h = hh * 64 + i;
        const float w = s_w[h];
        float4 p0 = *(const float4*)&s_pq[h][0];
        float4 p1 = *(const float4*)&s_pq[h][4];
        acc[0] = __builtin_fmaf(w, __builtin_amdgcn_rcpf(__builtin_fmaf(ek, p0.x, 1.0f)), acc[0]);
        acc[1] = __builtin_fmaf(w, __builtin_amdgcn_rcpf(__builtin_fmaf(ek, p0.y, 1.0f)), acc[1]);
        acc[2] = __builtin_fmaf(w, __builtin_amdgcn_rcpf(__builtin_fmaf(ek, p0.z, 1.0f)), acc[2]);
        acc[3] = __builtin_fmaf(w, __builtin_amdgcn_rcpf(__builtin_fmaf(ek, p0.w, 1.0f)), acc[3]);
        acc[4] = __builtin_fmaf(w, __builtin_amdgcn_rcpf(__builtin_fmaf(ek, p1.x, 1.0f)), acc[4]);
        acc[5] = __builtin_fmaf(w, __builtin_amdgcn_rcpf(__builtin_fmaf(ek, p1.y, 1.0f)), acc[5]);
        acc[6] = __builtin_fmaf(w, __builtin_amdgcn_rcpf(__builtin_fmaf(ek, p1.z, 1.0f)), acc[6]);
        acc[7] = __builtin_fmaf(w, __builtin_amdgcn_rcpf(__builtin_fmaf(ek, p1.w, 1.0f)), acc[7]);
    }

#pragma unroll
    for (int q = 0; q < 8; q++) s_part[hh][q][kl] = acc[q];
    __syncthreads();

    // epilogue: thread handles 4 q at its kl; waves 0,1 -> q 0-3; waves 2,3 -> q 4-7
    const int qb = (t >> 7) * 4;
    float* arow = attn + (size_t)(b * QN + q0 + qb) * KN + k;
    float psum[4];
#pragma unroll
    for (int j = 0; j < 4; j++) {
        const int q = qb + j;
        float tot = s_part[0][q][kl] + s_part[1][q][kl];
        float e = (k < valid) ? __builtin_amdgcn_exp2f(NL2E * tot) : 0.f;
        arow[(size_t)j * KN] = e;
#pragma unroll
        for (int off = 32; off > 0; off >>= 1) e += __shfl_xor(e, off, 64);
        psum[j] = e;
    }
    const int wv = t >> 6;
    if ((t & 63) == 0) {
#pragma unroll
        for (int j = 0; j < 4; j++) s_red[wv][j] = psum[j];
    }
    __syncthreads();
    if (t < 8) {
        const int q = t;
        float s = (q < 4) ? (s_red[0][q] + s_red[1][q])
                          : (s_red[2][q - 4] + s_red[3][q - 4]);
        pp[q * 8 + c] = s;
    }
}

// ---------------------------------------------------------------------------
// Kernel 3: out = normalize(e) @ values.  Grid = 4b x 32qt(8) x 4vq(64) = 512
// blocks, 256 threads = (k-half ks, q 0-7, 16 v-threads x float4).
// Both k-halves accumulate in parallel, LDS partial reduce, norm fused.
// ---------------------------------------------------------------------------
__global__ __launch_bounds__(256, 2) void av_kernel(const float* __restrict__ attn,
                                                    const float* __restrict__ partial,
                                                    const float* __restrict__ values,
                                                    const int* __restrict__ valid_lens,
                                                    float* __restrict__ out) {
    __shared__ float s_e[2][8][68];
    __shared__ float s_part[2][8][68];

    const int blk = blockIdx.x;
    const int b = blk & 3;
    const int q0 = ((blk >> 2) & 31) * 8;
    const int vb = blk >> 7;
    const int t = threadIdx.x;
    const int ks = t >> 7;
    const int q = (t >> 4) & 7;
    const int vt = (t & 15) * 4;
    const int voff = vb * 64 + vt;
    const int valid = valid_lens[b];

    const int lim0 = min(valid, 512);
    const int T0 = (lim0 + 63) >> 6;                  // tiles for half 0 (>= half 1)
    const int myLim = ks ? max(0, valid - 512) : lim0;
    const int myBeg = ks * 512;

    const float* arow = attn + (size_t)(b * QN + q0 + q) * KN + myBeg + vt;
    const float* vp = values + (size_t)b * KN * DIN + voff;

    float4 acc = {0.f, 0.f, 0.f, 0.f};
    for (int it = 0; it < T0; it++) {
        const int kt = it * 64;
        const bool act = kt < myLim;
        __syncthreads();
        if (act)
            *(float4*)&s_e[ks][q][vt] = *(const float4*)(arow + kt);
        __syncthreads();
        if (act) {
            const float* vk = vp + (size_t)(myBeg + kt) * DIN;
#pragma unroll 4
            for (int kk = 0; kk < 64; kk += 4) {
                float4 aw = *(const float4*)&s_e[ks][q][kk];
                float4 v0 = *(const float4*)(vk + (size_t)kk * DIN);
                float4 v1 = *(const float4*)(vk + (size_t)(kk + 1) * DIN);
                float4 v2 = *(const float4*)(vk + (size_t)(kk + 2) * DIN);
                float4 v3 = *(const float4*)(vk + (size_t)(kk + 3) * DIN);
                acc.x += aw.x * v0.x + aw.y * v1.x + aw.z * v2.x + aw.w * v3.x;
                acc.y += aw.x * v0.y + aw.y * v1.y + aw.z * v2.y + aw.w * v3.y;
                acc.z += aw.x * v0.z + aw.y * v1.z + aw.z * v2.z + aw.w * v3.z;
                acc.w += aw.x * v0.w + aw.y * v1.w + aw.z * v2.w + aw.w * v3.w;
            }
        }
    }

    *(float4*)&s_part[ks][q][vt] = acc;
    __syncthreads();
    if (t < 128) {
        const int q2 = t >> 4, v4 = (t & 15) * 4;
        float4 a0 = *(const float4*)&s_part[0][q2][v4];
        float4 a1 = *(const float4*)&s_part[1][q2][v4];
        const float* pr = partial + (size_t)(b * QN + q0 + q2) * 8;
        float4 pA = *(const float4*)pr;
        float4 pB = *(const float4*)(pr + 4);
        const float inv = 1.0f / (pA.x + pA.y + pA.z + pA.w + pB.x + pB.y + pB.z + pB.w);
        float4 o;
        o.x = (a0.x + a1.x) * inv;
        o.y = (a0.y + a1.y) * inv;
        o.z = (a0.z + a1.z) * inv;
        o.w = (a0.w + a1.w) * inv;
        *(float4*)(out + (size_t)(b * QN + q0 + q2) * DIN + vb * 64 + v4) = o;
    }
}

extern "C" void kernel_launch(void* const* d_in, const int* in_sizes, int n_in,
                              void* d_out, int out_size, void* d_ws, size_t ws_size,
                              hipStream_t stream) {
    const float* queries    = (const float*)d_in[0];
    const float* keys       = (const float*)d_in[1];
    const float* values     = (const float*)d_in[2];
    const int*   valid_lens = (const int*)d_in[3];
    const float* W_q        = (const float*)d_in[4];
    const float* W_k        = (const float*)d_in[5];
    const float* w_v        = (const float*)d_in[6];
    float* out = (float*)d_out;

    float* Eq      = (float*)d_ws;                    // [B*QN][HD]    512 KB
    float* EkT     = Eq + (size_t)BQ * QN * HD;       // [B][HD][KN]     2 MB
    float* attn    = EkT + (size_t)BQ * HD * KN;      // [B*QN][KN]      4 MB
    float* partial = attn + (size_t)BQ * QN * KN;     // [B*QN][8]      32 KB

    proj_kernel<<<(BQ * QN + BQ * KN) / 32, 256, 0, stream>>>(queries, keys, W_q, W_k, Eq, EkT);
    score_kernel<<<BQ * (QN / 8) * 8, 256, 0, stream>>>(Eq, EkT, valid_lens, w_v, attn, partial);
    av_kernel<<<BQ * (QN / 8) * 4, 256, 0, stream>>>(attn, partial, values, valid_lens, out);
}

// Round 6
// 127.882 us; speedup vs baseline: 1.9401x; 1.0002x over previous
//
#include <hip/hip_runtime.h>
#include <math.h>

#define BQ   4
#define QN   256
#define KN   1024
#define DIN  256     // Q_SIZE == K_SIZE == V_SIZE
#define HD   128     // H

// C2 = 2*log2(e): exp2(C2*x) = e^{2x}
#define C2F   2.8853900817779268f
#define NL2E  (-2.8853900817779268f)

// ---------------------------------------------------------------------------
// Kernel 1: projections as tiled GEMM, outputs in EXP2 DOMAIN:
//   Eq  [b*QN+q][h]      = exp2(C2*qp)                     (row-major)
//   EkT4[b][h/4][k][4]   = exp2(C2*kp)   (4 consecutive h packed per float4,
//                                         so score does 1 dwordx4 per 4 h)
// Block = 32 rows x 128 h, 256 threads, thread = 4x4 = 16 acc.
// ---------------------------------------------------------------------------
__global__ __launch_bounds__(256, 2) void proj_kernel(const float* __restrict__ queries,
                                                      const float* __restrict__ keys,
                                                      const float* __restrict__ W_q,
                                                      const float* __restrict__ W_k,
                                                      float* __restrict__ Eq,
                                                      float* __restrict__ EkT4) {
    __shared__ float xT[32][36];    // [k][row]
    __shared__ float WT[32][136];   // [k][h]

    const int t = threadIdx.x;
    const int row0 = blockIdx.x * 32;
    const bool is_q = row0 < BQ * QN;
    const float* x = is_q ? queries : keys;
    const float* W = is_q ? W_q : W_k;
    const int xr0 = is_q ? row0 : row0 - BQ * QN;

    const int h0 = (t & 31) * 4;
    const int r0 = (t >> 5) * 4;

    float acc[4][4];
#pragma unroll
    for (int r = 0; r < 4; r++)
#pragma unroll
        for (int c = 0; c < 4; c++) acc[r][c] = 0.f;

    for (int ks = 0; ks < DIN; ks += 32) {
        __syncthreads();
        {   // x[32 rows][32 k] -> xT[k][row]
            const int r = t >> 3, k4 = (t & 7) * 4;
            float4 xv = *(const float4*)(x + (size_t)(xr0 + r) * DIN + ks + k4);
            xT[k4 + 0][r] = xv.x; xT[k4 + 1][r] = xv.y;
            xT[k4 + 2][r] = xv.z; xT[k4 + 3][r] = xv.w;
        }
#pragma unroll
        for (int u = 0; u < 4; u++) {   // W[128 h][32 k] -> WT[k][h]
            const int h = (t >> 3) + 32 * u, k4 = (t & 7) * 4;
            float4 wv = *(const float4*)(W + (size_t)h * DIN + ks + k4);
            WT[k4 + 0][h] = wv.x; WT[k4 + 1][h] = wv.y;
            WT[k4 + 2][h] = wv.z; WT[k4 + 3][h] = wv.w;
        }
        __syncthreads();
#pragma unroll
        for (int kk = 0; kk < 32; kk++) {
            float4 xv = *(const float4*)&xT[kk][r0];
            float4 wv = *(const float4*)&WT[kk][h0];
            const float xr[4] = {xv.x, xv.y, xv.z, xv.w};
            const float wc[4] = {wv.x, wv.y, wv.z, wv.w};
#pragma unroll
            for (int r = 0; r < 4; r++)
#pragma unroll
                for (int c = 0; c < 4; c++)
                    acc[r][c] = __builtin_fmaf(xr[r], wc[c], acc[r][c]);
        }
    }

    if (is_q) {
#pragma unroll
        for (int r = 0; r < 4; r++) {
            float4 o;
            o.x = __builtin_amdgcn_exp2f(C2F * acc[r][0]);
            o.y = __builtin_amdgcn_exp2f(C2F * acc[r][1]);
            o.z = __builtin_amdgcn_exp2f(C2F * acc[r][2]);
            o.w = __builtin_amdgcn_exp2f(C2F * acc[r][3]);
            *(float4*)(Eq + (size_t)(row0 + r0 + r) * HD + h0) = o;
        }
    } else {
        const int krow = row0 - BQ * QN;
        const int b = krow >> 10, k0 = (krow & (KN - 1)) + r0;
        const int h4 = t & 31;                      // h-quad index = h0/4
        float* base = EkT4 + ((size_t)(b * 32 + h4) * KN + k0) * 4;
#pragma unroll
        for (int r = 0; r < 4; r++) {
            float4 o;
            o.x = __builtin_amdgcn_exp2f(C2F * acc[r][0]);
            o.y = __builtin_amdgcn_exp2f(C2F * acc[r][1]);
            o.z = __builtin_amdgcn_exp2f(C2F * acc[r][2]);
            o.w = __builtin_amdgcn_exp2f(C2F * acc[r][3]);
            *(float4*)(base + (size_t)r * 4) = o;   // consecutive k
        }
    }
}

// ---------------------------------------------------------------------------
// Kernel 2: scores -> unnormalized e + per-chunk row sums.
// Grid = 4b x 32 q-tiles(8) x 8 k-chunks(128) = 1024 blocks, 256 threads.
// Thread = (k-lane kl = t&127, h-half hh = t>>7); 16 dwordx4 loads/thread
// (4 h per load), 32 rcp-chains (3 VALU) per load -> latency fully covered.
// e = 0 for k >= valid; per-chunk partial sums -> ws (deterministic).
// ---------------------------------------------------------------------------
__global__ __launch_bounds__(256, 4) void score_kernel(const float* __restrict__ Eq,
                                                       const float* __restrict__ EkT4,
                                                       const int* __restrict__ valid_lens,
                                                       const float* __restrict__ w_v,
                                                       float* __restrict__ attn,
                                                       float* __restrict__ partial) {
    __shared__ float s_w[HD];
    __shared__ float s_pq[HD][8];
    __shared__ float s_part[2][8][128];
    __shared__ float s_red[4][4];

    const int blk = blockIdx.x;
    const int b = blk & 3;
    const int q0 = ((blk >> 2) & 31) * 8;
    const int c = blk >> 7;            // 0..7
    const int t = threadIdx.x;
    const int valid = valid_lens[b];
    float* pp = partial + (size_t)(b * QN + q0) * 8;

    if (c * 128 >= valid) {            // fully masked chunk: attn never read here
        if (t < 8) pp[t * 8 + c] = 0.f;
        return;
    }

    const int kl = t & 127;
    const int hh = t >> 7;
    const int k = c * 128 + kl;

    if (t < HD) s_w[t] = w_v[t];
    {
        const int h = t & 127;
#pragma unroll
        for (int j = 0; j < 4; j++) {
            const int q = (t >> 7) * 4 + j;
            s_pq[h][q] = Eq[(size_t)(b * QN + q0 + q) * HD + h];
        }
    }
    __syncthreads();

    // 4 h per dwordx4: quad index = b*32 + hh*16 + i
    const float4* kcol = (const float4*)EkT4 + ((size_t)(b * 32 + hh * 16) * KN + k);
    float acc[8] = {0.f, 0.f, 0.f, 0.f, 0.f, 0.f, 0.f, 0.f};

#pragma unroll 4
    for (int i = 0; i < 16; i++) {
        float4 ek4 = kcol[(size_t)i * KN];
        const int hb = hh * 64 + i * 4;
        const float ekv[4] = {ek4.x, ek4.y, ek4.z, ek4.w};
#pragma unroll
        for (int j = 0; j < 4; j++) {
            const float ek = ekv[j];
            const float w = s_w[hb + j];
            float4 p0 = *(const float4*)&s_pq[hb + j][0];
            float4 p1 = *(const float4*)&s_pq[hb + j][4];
            acc[0] = __builtin_fmaf(w, __builtin_amdgcn_rcpf(__builtin_fmaf(ek, p0.x, 1.0f)), acc[0]);
            acc[1] = __builtin_fmaf(w, __builtin_amdgcn_rcpf(__builtin_fmaf(ek, p0.y, 1.0f)), acc[1]);
            acc[2] = __builtin_fmaf(w, __builtin_amdgcn_rcpf(__builtin_fmaf(ek, p0.z, 1.0f)), acc[2]);
            acc[3] = __builtin_fmaf(w, __builtin_amdgcn_rcpf(__builtin_fmaf(ek, p0.w, 1.0f)), acc[3]);
            acc[4] = __builtin_fmaf(w, __builtin_amdgcn_rcpf(__builtin_fmaf(ek, p1.x, 1.0f)), acc[4]);
            acc[5] = __builtin_fmaf(w, __builtin_amdgcn_rcpf(__builtin_fmaf(ek, p1.y, 1.0f)), acc[5]);
            acc[6] = __builtin_fmaf(w, __builtin_amdgcn_rcpf(__builtin_fmaf(ek, p1.z, 1.0f)), acc[6]);
            acc[7] = __builtin_fmaf(w, __builtin_amdgcn_rcpf(__builtin_fmaf(ek, p1.w, 1.0f)), acc[7]);
        }
    }

#pragma unroll
    for (int q = 0; q < 8; q++) s_part[hh][q][kl] = acc[q];
    __syncthreads();

    // epilogue: waves 0,1 -> q 0-3; waves 2,3 -> q 4-7 (at this thread's kl)
    const int qb = (t >> 7) * 4;
    float* arow = attn + (size_t)(b * QN + q0 + qb) * KN + k;
    float psum[4];
#pragma unroll
    for (int j = 0; j < 4; j++) {
        const int q = qb + j;
        float tot = s_part[0][q][kl] + s_part[1][q][kl];
        float e = (k < valid) ? __builtin_amdgcn_exp2f(NL2E * tot) : 0.f;
        arow[(size_t)j * KN] = e;
#pragma unroll
        for (int off = 32; off > 0; off >>= 1) e += __shfl_xor(e, off, 64);
        psum[j] = e;
    }
    const int wv = t >> 6;
    if ((t & 63) == 0) {
#pragma unroll
        for (int j = 0; j < 4; j++) s_red[wv][j] = psum[j];
    }
    __syncthreads();
    if (t < 8) {
        const int q = t;
        float s = (q < 4) ? (s_red[0][q] + s_red[1][q])
                          : (s_red[2][q - 4] + s_red[3][q - 4]);
        pp[q * 8 + c] = s;
    }
}

// ---------------------------------------------------------------------------
// Kernel 3: out = normalize(e) @ values.  Grid = 4b x 32qt(8) x 4vq(64) = 512
// blocks, 256 threads = (k-half ks, q 0-7, 16 v-threads x float4).
// Both k-halves accumulate in parallel, LDS partial reduce, norm fused.
// ---------------------------------------------------------------------------
__global__ __launch_bounds__(256, 2) void av_kernel(const float* __restrict__ attn,
                                                    const float* __restrict__ partial,
                                                    const float* __restrict__ values,
                                                    const int* __restrict__ valid_lens,
                                                    float* __restrict__ out) {
    __shared__ float s_e[2][8][68];
    __shared__ float s_part[2][8][68];

    const int blk = blockIdx.x;
    const int b = blk & 3;
    const int q0 = ((blk >> 2) & 31) * 8;
    const int vb = blk >> 7;
    const int t = threadIdx.x;
    const int ks = t >> 7;
    const int q = (t >> 4) & 7;
    const int vt = (t & 15) * 4;
    const int voff = vb * 64 + vt;
    const int valid = valid_lens[b];

    const int lim0 = min(valid, 512);
    const int T0 = (lim0 + 63) >> 6;                  // tiles for half 0 (>= half 1)
    const int myLim = ks ? max(0, valid - 512) : lim0;
    const int myBeg = ks * 512;

    const float* arow = attn + (size_t)(b * QN + q0 + q) * KN + myBeg + vt;
    const float* vp = values + (size_t)b * KN * DIN + voff;

    float4 acc = {0.f, 0.f, 0.f, 0.f};
    for (int it = 0; it < T0; it++) {
        const int kt = it * 64;
        const bool act = kt < myLim;
        __syncthreads();
        if (act)
            *(float4*)&s_e[ks][q][vt] = *(const float4*)(arow + kt);
        __syncthreads();
        if (act) {
            const float* vk = vp + (size_t)(myBeg + kt) * DIN;
#pragma unroll 4
            for (int kk = 0; kk < 64; kk += 4) {
                float4 aw = *(const float4*)&s_e[ks][q][kk];
                float4 v0 = *(const float4*)(vk + (size_t)kk * DIN);
                float4 v1 = *(const float4*)(vk + (size_t)(kk + 1) * DIN);
                float4 v2 = *(const float4*)(vk + (size_t)(kk + 2) * DIN);
                float4 v3 = *(const float4*)(vk + (size_t)(kk + 3) * DIN);
                acc.x += aw.x * v0.x + aw.y * v1.x + aw.z * v2.x + aw.w * v3.x;
                acc.y += aw.x * v0.y + aw.y * v1.y + aw.z * v2.y + aw.w * v3.y;
                acc.z += aw.x * v0.z + aw.y * v1.z + aw.z * v2.z + aw.w * v3.z;
                acc.w += aw.x * v0.w + aw.y * v1.w + aw.z * v2.w + aw.w * v3.w;
            }
        }
    }

    *(float4*)&s_part[ks][q][vt] = acc;
    __syncthreads();
    if (t < 128) {
        const int q2 = t >> 4, v4 = (t & 15) * 4;
        float4 a0 = *(const float4*)&s_part[0][q2][v4];
        float4 a1 = *(const float4*)&s_part[1][q2][v4];
        const float* pr = partial + (size_t)(b * QN + q0 + q2) * 8;
        float4 pA = *(const float4*)pr;
        float4 pB = *(const float4*)(pr + 4);
        const float inv = 1.0f / (pA.x + pA.y + pA.z + pA.w + pB.x + pB.y + pB.z + pB.w);
        float4 o;
        o.x = (a0.x + a1.x) * inv;
        o.y = (a0.y + a1.y) * inv;
        o.z = (a0.z + a1.z) * inv;
        o.w = (a0.w + a1.w) * inv;
        *(float4*)(out + (size_t)(b * QN + q0 + q2) * DIN + vb * 64 + v4) = o;
    }
}

extern "C" void kernel_launch(void* const* d_in, const int* in_sizes, int n_in,
                              void* d_out, int out_size, void* d_ws, size_t ws_size,
                              hipStream_t stream) {
    const float* queries    = (const float*)d_in[0];
    const float* keys       = (const float*)d_in[1];
    const float* values     = (const float*)d_in[2];
    const int*   valid_lens = (const int*)d_in[3];
    const float* W_q        = (const float*)d_in[4];
    const float* W_k        = (const float*)d_in[5];
    const float* w_v        = (const float*)d_in[6];
    float* out = (float*)d_out;

    float* Eq      = (float*)d_ws;                    // [B*QN][HD]    512 KB
    float* EkT4    = Eq + (size_t)BQ * QN * HD;       // [B][32][KN][4]  2 MB
    float* attn    = EkT4 + (size_t)BQ * HD * KN;     // [B*QN][KN]      4 MB
    float* partial = attn + (size_t)BQ * QN * KN;     // [B*QN][8]      32 KB

    proj_kernel<<<(BQ * QN + BQ * KN) / 32, 256, 0, stream>>>(queries, keys, W_q, W_k, Eq, EkT4);
    score_kernel<<<BQ * (QN / 8) * 8, 256, 0, stream>>>(Eq, EkT4, valid_lens, w_v, attn, partial);
    av_kernel<<<BQ * (QN / 8) * 4, 256, 0, stream>>>(attn, partial, values, valid_lens, out);
}